// Round 7
// baseline (1797.813 us; speedup 1.0000x reference)
//
#include <hip/hip_runtime.h>
#include <math.h>

#define N 8192
#define D 256
#define LN2 0.6931471805599453f

typedef short short8 __attribute__((ext_vector_type(8)));
typedef float f32x16 __attribute__((ext_vector_type(16)));
typedef unsigned short ushort;

__device__ __forceinline__ float fexp2(float x) { return __builtin_amdgcn_exp2f(x); }
__device__ __forceinline__ float flog2(float x) { return __builtin_amdgcn_logf(x); }

__device__ __forceinline__ ushort bf16r(float x) {  // RNE f32 -> bf16
    unsigned int u = __float_as_uint(x);
    return (ushort)((u + 0x7FFF + ((u >> 16) & 1)) >> 16);
}

__device__ __forceinline__ void gl_lds16(const ushort* g, ushort* l) {
    __builtin_amdgcn_global_load_lds(
        (const __attribute__((address_space(1))) unsigned int*)g,
        (__attribute__((address_space(3))) unsigned int*)l, 16, 0, 0);
}

// ---------------- weight clip + renormalize ----------------
__global__ void prep_wc(const float* __restrict__ w, float* __restrict__ wc) {
    int t = threadIdx.x;  // 256
    float v = fminf(fmaxf(w[t], 0.0f), 2.0f);
    float s = v;
#pragma unroll
    for (int m = 1; m < 64; m <<= 1) s += __shfl_xor(s, m);
    __shared__ float sm[4];
    if ((t & 63) == 0) sm[t >> 6] = s;
    __syncthreads();
    float mean = (sm[0] + sm[1] + sm[2] + sm[3]) * (1.0f / 256.0f);
    wc[t] = v / mean;
}

// ---------------- normalize rows -> bf16 panels ----------------
__global__ void prep_normalize(const float* __restrict__ x1, const float* __restrict__ x2,
                               const float* __restrict__ wc,
                               ushort* __restrict__ an_i, ushort* __restrict__ bn_i) {
    int row = blockIdx.x;  // 0..16383
    int t = threadIdx.x;   // 0..255
    int r; float v; ushort* ip;
    if (row < N) { r = row;     v = x1[(size_t)r * D + t] * wc[t]; ip = an_i; }
    else         { r = row - N; v = x2[(size_t)r * D + t];         ip = bn_i; }
    float ss = v * v;
#pragma unroll
    for (int m = 1; m < 64; m <<= 1) ss += __shfl_xor(ss, m);
    __shared__ float sm[4];
    if ((t & 63) == 0) sm[t >> 6] = ss;
    __syncthreads();
    float denom = sqrtf(sm[0] + sm[1] + sm[2] + sm[3]) + 1e-12f;
    ip[(size_t)r * D + t] = bf16r(v / denom);
}

// ---------------- pots init: pot=0, potm1=-1 ----------------
__global__ void init_pots(float* __restrict__ pots, float* __restrict__ potm1) {
    int id = blockIdx.x * 256 + threadIdx.x;
    pots[id] = 0.0f;
    potm1[id] = -1.0f;
}

// ---------------- fused cost + softmin via MFMA, LDS-staged j-tiles ----------------
// tasks: 0: fxx (j=an,i=an)  1: gyy (j=bn,i=bn)  2: f (j=bn,i=an, pot=g)  3: g (j=an,i=bn, pot=f)
// R5-verified dataflow. Changes: XOR-swizzled LDS (slot c holds global chunk c^(row&7)),
// 64 j's per barrier interval (2 j-tiles per 32 KB buffer -> 32 barriers instead of 64),
// tree-reduced epilogue (4-level max/sum trees vs 15-deep serial chains).
__global__ __launch_bounds__(256, 2) void softmin_mfma(
    const ushort* __restrict__ an_i, const ushort* __restrict__ bn_i,
    const float* __restrict__ potm1,
    float2* __restrict__ parts, float k1) {  // k1 = log2(e)/eps
    int bx = blockIdx.x;          // 512 blocks
    int k = bx & 7;               // XCD slot: (task, split-pair) fixed per XCD
    int q = bx >> 3;              // 0..63
    int task = k >> 1;
    int split = ((k & 1) << 1) | (q & 1);
    int rb = q >> 1;              // 0..31
    const ushort* jp = (task == 0 || task == 3) ? an_i : bn_i;
    const ushort* ip = (task == 0 || task == 2) ? an_i : bn_i;
    const float* pm1 = potm1 + (size_t)task * N;

    int t = threadIdx.x;
    int wave = t >> 6, lane = t & 63;
    int l31 = lane & 31, lh = lane >> 5;
    int xk = l31 & 7;
    int i0 = rb * 256 + wave * 64;  // this wave: rows [i0, i0+64)

    __shared__ ushort lbuf[2][2048 * 8];  // 32 KB per buffer: 64 j-rows x 32 slots x 16 B

    // i-side (B_op) fragments, K=256 (16 chunks), two 32-row sets -> pin into AGPRs
    short8 bi0[16], bi1[16];
    {
        const ushort* ib = ip + (size_t)(i0 + l31) * D + lh * 8;
#pragma unroll
        for (int c = 0; c < 16; ++c) {
            bi0[c] = *(const short8*)(ib + c * 16);
            bi1[c] = *(const short8*)(ib + (size_t)32 * D + c * 16);
        }
    }
#pragma unroll
    for (int c = 0; c < 16; ++c) {
        asm volatile("" : "+a"(bi0[c]), "+a"(bi1[c]));  // force AGPR residency
    }

    const int jbase0 = split * 2048;

    // stage 64 j-rows (2 tiles) into LDS buffer b with XOR swizzle
    auto stage = [&](int b, int iv) {
        const ushort* gb = jp + (size_t)(jbase0 + iv * 64) * D;
        ushort* lbp = &lbuf[b][0];
#pragma unroll
        for (int r = 0; r < 8; ++r) {
            int s = r * 256 + t;          // 16-B slot index, 0..2047 (contiguous per wave -> lane*16)
            int row = s >> 5;             // 0..63
            int c = s & 31;
            int csrc = c ^ (row & 7);     // source chunk for this slot
            gl_lds16(gb + (size_t)row * D + csrc * 8, lbp + s * 8);
        }
    };

    float m0 = -INFINITY, s0 = 0.0f, m1 = -INFINITY, s1 = 0.0f;

    // tree-reduced online-LSE epilogue (base 2), one i-row per lane per tile
    auto epi = [&](const f32x16& acc, const float* pj, float& mR, float& sR) {
        float tv[16];
#pragma unroll
        for (int r = 0; r < 16; ++r) tv[r] = fmaf(acc[r], k1, pj[r]);
        float x0 = fmaxf(tv[0], tv[1]),  x1 = fmaxf(tv[2], tv[3]),
              x2 = fmaxf(tv[4], tv[5]),  x3 = fmaxf(tv[6], tv[7]),
              x4 = fmaxf(tv[8], tv[9]),  x5 = fmaxf(tv[10], tv[11]),
              x6 = fmaxf(tv[12], tv[13]), x7 = fmaxf(tv[14], tv[15]);
        float y0 = fmaxf(x0, x1), y1 = fmaxf(x2, x3),
              y2 = fmaxf(x4, x5), y3 = fmaxf(x6, x7);
        float tm = fmaxf(fmaxf(y0, y1), fmaxf(y2, y3));
        float mn = fmaxf(mR, tm);
        float e[16];
#pragma unroll
        for (int r = 0; r < 16; ++r) e[r] = fexp2(tv[r] - mn);
        float sA = (e[0] + e[1]) + (e[2] + e[3]),   sB = (e[4] + e[5]) + (e[6] + e[7]),
              sC = (e[8] + e[9]) + (e[10] + e[11]), sD = (e[12] + e[13]) + (e[14] + e[15]);
        float ad = (sA + sB) + (sC + sD);
        sR = fmaf(sR, fexp2(mR - mn), ad);
        mR = mn;
    };

    stage(0, 0);
    for (int iv = 0; iv < 32; ++iv) {    // 64 j's per interval
        int cur = iv & 1;
        __syncthreads();                 // drains prev interval's prefetch (issued a full interval ago)
        if (iv < 31) stage(cur ^ 1, iv + 1);

#pragma unroll
        for (int u = 0; u < 2; ++u) {
            int j0 = jbase0 + iv * 64 + u * 32;
            float pjk[16];
#pragma unroll
            for (int g = 0; g < 4; ++g) {
                float4 pv = *(const float4*)&pm1[j0 + 8 * g + 4 * lh];
                pjk[4 * g + 0] = pv.x * k1; pjk[4 * g + 1] = pv.y * k1;
                pjk[4 * g + 2] = pv.z * k1; pjk[4 * g + 3] = pv.w * k1;
            }
            const ushort* lb = &lbuf[cur][(u * 32 + l31) * 256];  // row base: 32 slots x 8 ushorts
            f32x16 acc0 = {}; f32x16 acc1 = {};
#pragma unroll
            for (int c = 0; c < 16; ++c) {
                int sl = (2 * c + lh) ^ xk;            // swizzled 16-B slot within row
                short8 af = *(const short8*)(lb + sl * 8);
                acc0 = __builtin_amdgcn_mfma_f32_32x32x16_bf16(af, bi0[c], acc0, 0, 0, 0);
                acc1 = __builtin_amdgcn_mfma_f32_32x32x16_bf16(af, bi1[c], acc1, 0, 0, 0);
            }
            epi(acc0, pjk, m0, s0);
            epi(acc1, pjk, m1, s1);
        }
    }
    // lanes l and l+32 hold disjoint j-subsets of the same i-row: merge
    float mo = __shfl_xor(m0, 32), so = __shfl_xor(s0, 32);
    float M0 = fmaxf(m0, mo);
    float S0 = s0 * fexp2(m0 - M0) + so * fexp2(mo - M0);
    mo = __shfl_xor(m1, 32); so = __shfl_xor(s1, 32);
    float M1 = fmaxf(m1, mo);
    float S1 = s1 * fexp2(m1 - M1) + so * fexp2(mo - M1);
    if (lane < 32) {
        size_t r0 = (size_t)task * N + (i0 + l31);
        size_t r1 = r0 + 32;
        parts[r0 * 4 + split] = make_float2(M0, S0);
        parts[r1 * 4 + split] = make_float2(M1, S1);
    }
}

// ---------------- merge j-split partials -> new potentials + consumer potm1 ----------------
__global__ void merge_pots(const float2* __restrict__ parts, float* __restrict__ pots,
                           float* __restrict__ potm1, float eps, float logw, int do_avg) {
    int id = blockIdx.x * 256 + threadIdx.x;  // id = task*N + row
    int task = id >> 13;
    int row = id & (N - 1);
    const float2* p = parts + (size_t)id * 4;
    float2 a = p[0], b = p[1], c = p[2], d = p[3];
    float M = fmaxf(fmaxf(a.x, b.x), fmaxf(c.x, d.x));
    float S = a.y * fexp2(a.x - M) + b.y * fexp2(b.x - M) +
              c.y * fexp2(c.x - M) + d.y * fexp2(d.x - M);
    float lse = LN2 * (M + flog2(S));      // natural-log LSE
    float v = -eps * (logw + lse);
    if (do_avg && task < 2) v = 0.5f * (pots[id] + v);
    pots[id] = v;
    // consumer mapping: fxx->task0, gyy->task1, f (task2) streamed by task3, g (task3) by task2
    int ct = (task < 2) ? task : (5 - task);
    potm1[(size_t)ct * N + row] = v - 1.0f;
}

// ---------------- final scalar reduce ----------------
__global__ void final_reduce(const float* __restrict__ pots, float* __restrict__ out) {
    int t = threadIdx.x;
    float s = 0.0f;
    for (int i = t; i < N; i += 256)
        s += (pots[2 * N + i] - pots[i]) + (pots[3 * N + i] - pots[N + i]);
#pragma unroll
    for (int m = 1; m < 64; m <<= 1) s += __shfl_xor(s, m);
    __shared__ float sm[4];
    if ((t & 63) == 0) sm[t >> 6] = s;
    __syncthreads();
    if (t == 0) out[0] = (sm[0] + sm[1] + sm[2] + sm[3]) * (1.0f / (float)N);
}

extern "C" void kernel_launch(void* const* d_in, const int* in_sizes, int n_in,
                              void* d_out, int out_size, void* d_ws, size_t ws_size,
                              hipStream_t stream) {
    const float* x1 = (const float*)d_in[0];
    const float* x2 = (const float*)d_in[1];
    const float* w  = (const float*)d_in[2];
    float* out = (float*)d_out;

    ushort* an_i = (ushort*)d_ws;                       // N*D bf16
    ushort* bn_i = an_i + (size_t)N * D;                // N*D
    float*  wc   = (float*)(bn_i + (size_t)N * D);      // 256
    float*  pots = wc + 256;                            // 4N (fxx,gyy,f,g)
    float*  potm1 = pots + 4 * N;                       // 4N (consumer-indexed pot-1)
    float2* parts = (float2*)(potm1 + 4 * N);           // 4N * 4 splits

    prep_wc<<<1, 256, 0, stream>>>(w, wc);
    prep_normalize<<<2 * N, 256, 0, stream>>>(x1, x2, wc, an_i, bn_i);
    init_pots<<<4 * N / 256, 256, 0, stream>>>(pots, potm1);

    const float eps_list[10] = {4.0f, 1.0f, 0.25f, 0.0625f, 0.015625f,
                                0.00390625f, 0.0025f, 0.0025f, 0.0025f, 0.0025f};
    const float logw = -logf((float)N);
    const float LOG2E = 1.4426950408889634f;
    for (int it = 0; it < 10; ++it) {
        softmin_mfma<<<512, 256, 0, stream>>>(an_i, bn_i, potm1, parts, LOG2E / eps_list[it]);
        merge_pots<<<4 * N / 256, 256, 0, stream>>>(parts, pots, potm1,
                                                    eps_list[it], logw, 1);
    }
    // final extrapolation at eps_final, no averaging
    softmin_mfma<<<512, 256, 0, stream>>>(an_i, bn_i, potm1, parts, LOG2E / 0.0025f);
    merge_pots<<<4 * N / 256, 256, 0, stream>>>(parts, pots, potm1, 0.0025f, logw, 0);
    final_reduce<<<1, 256, 0, stream>>>(pots, out);
}